// Round 1
// baseline (432.980 us; speedup 1.0000x reference)
//
#include <hip/hip_runtime.h>

namespace {

constexpr int BD = 2;
constexpr int DD = 160, HH = 192, WW = 224;
constexpr float INV_WIN = 1.0f / 729.0f;
constexpr float EPSV = 1e-5f;

constexpr int TH = 16, TW = 16;          // output tile (H x W)
constexpr int DC = 16;                   // output planes per d-chunk
constexpr int NREAL = DC + 8;            // 24 input plane steps (single-plane supersteps)
constexpr int NCH = DD / DC;             // 10
constexpr int GX = WW / TW;              // 14
constexpr int GY = HH / TH;              // 12
constexpr int GZ = BD * NCH;             // 20
constexpr int NBLK = GX * GY * GZ;       // 3360
constexpr int NXCD = 8;
constexpr int CPX = NBLK / NXCD;         // 420 (NBLK % 8 == 0 -> bijective swizzle)
constexpr double NTOT = (double)BD * DD * HH * WW;

// srow: [parity][field][w*28 + row], rows 0..23 (pad 28). Per-plane layout
// identical to the audited pair version (SR_FS=452: f-shift/4=113==1 mod 8;
// parity stride SR_PL=2280 is wave-uniform -> no bank effect).
// S2 b32 scatter 2/bank; S3 b128 reads uniform /quad.
constexpr int SR_FS = 452;
constexpr int SR_PL = 2280;
// scol: [parity][field][w*20 + oh]. SC_FS=324. S3 b128 writes uniform /quad;
// S4 b32 reads exactly 2/bank. Parity stride SC_PL=1620 wave-uniform.
constexpr int SC_FS = 324;
constexpr int SC_PL = 1620;

} // namespace

// Single-plane supersteps, ONE barrier per superstep:
//   iter ss: [prefetch(ss+1) | S2(ss)->srow[ss&1] | S3(ss-1): srow[(ss-1)&1]->scol[(ss-1)&1]]
//            barrier
//            [S4(ss-1): read scol[(ss-1)&1]]
// Hazard matrix (all separated by the single barrier C):
//   S2(ss) W srow[ss&1]      vs S3(ss-1) R srow[(ss-1)&1] : different parity, same epoch OK
//   S3(ss) R srow[ss&1]      vs S2(ss)   W                : C(ss) between
//   S2(ss+2) W srow[ss&1]    vs S3(ss)   R                : C(ss+1) between
//   S4(ss-1) R scol[(ss-1)&1] vs S3(ss-1) W               : C(ss) between
//   S3(ss) W scol[ss&1]      vs S4(ss-1) R (other parity) : same epoch OK
//   S3(ss+1) W scol[ss&1]    vs S4(ss-2) R scol[ss&1]     : C(ss) between
// LDS: 2*2280*4 + 2*1620*4 + 16 = 31216 B -> 5 blocks/CU (was 49.7 KB -> 3).
__global__ __launch_bounds__(256, 5)
void ncc_fused(const float* __restrict__ x, const float* __restrict__ y,
               float* __restrict__ bsum) {
  const int tid = threadIdx.x;

  // XCD-chunked swizzle: consecutive hardware blocks round-robin XCDs; give
  // each XCD a contiguous chunk of the (x,y,z) space so W/H-halo re-reads of
  // neighbor tiles hit the same-XCD L2.
  const int lid = (int)blockIdx.x;
  const int nl  = (lid & (NXCD - 1)) * CPX + (lid >> 3);
  const int zb  = nl / (GX * GY);
  const int rem = nl - zb * (GX * GY);
  const int by  = rem / GX;
  const int bx  = rem - by * GX;

  const int w0 = bx * TW;
  const int h0 = by * TH;
  const int b  = zb / NCH;
  const int d0 = (zb - b * NCH) * DC;

  __shared__ __align__(16) float srowF[2][SR_PL];  // 18240 B
  __shared__ __align__(16) float scolF[2][SC_PL];  // 12960 B
  __shared__ float swsum[4];

  // ---- S2 roles: tids 0..95 = 24 rows x 4 col-segments, 12-wide register
  // window -> 4 sliding 9-tap W-sums x 5 fields (one plane per superstep).
  const bool s2a = tid < 96;
  const int r2  = tid >> 2;            // input row 0..23
  const int seg = tid & 3;
  const int gh  = h0 - 4 + r2;
  const int gw0 = w0 - 4 + seg * 4;    // 16B aligned
  const bool hok = (unsigned)gh < (unsigned)HH;
  const bool fastw = (gw0 >= 0) && (gw0 + 11 < WW);
  const unsigned plane = (unsigned)HH * WW;

  auto prefetch = [&](int s, float4* vx, float4* vy) {
    const int din = d0 - 4 + s;
    const float4 z = make_float4(0.f, 0.f, 0.f, 0.f);
    vx[0] = vx[1] = vx[2] = z;
    vy[0] = vy[1] = vy[2] = z;
    if (s2a && hok && (din >= 0) && (din < DD)) {
      const unsigned rb = ((unsigned)b * DD + (unsigned)din) * plane + (unsigned)gh * WW;
      if (fastw) {
        const float4* px = (const float4*)(x + rb + gw0);
        const float4* py = (const float4*)(y + rb + gw0);
        vx[0] = px[0]; vx[1] = px[1]; vx[2] = px[2];
        vy[0] = py[0]; vy[1] = py[1]; vy[2] = py[2];
      } else {
        float* fx = (float*)vx;
        float* fy = (float*)vy;
#pragma unroll
        for (int e = 0; e < 12; ++e) {
          const int gw = gw0 + e;
          if ((unsigned)gw < (unsigned)WW) {
            fx[e] = x[rb + gw];
            fy[e] = y[rb + gw];
          }
        }
      }
    }
  };

  // ---- S3 roles: tids 96..175 = 5 fields x 16 w (disjoint from S2 threads;
  // wave0: S2, wave1: half S2 + half S3, wave2: 3/4 S3, wave3: S4-only).
  const bool s3a = (tid >= 96) && (tid < 176);
  const int t3  = tid - 96;
  const int f3  = t3 >> 4;
  const int wl3 = t3 & 15;

  const int ow = tid & 15;
  const int oh = tid >> 4;

  // D-ring: 9 slots x 5 fields; slot indices static after full unroll.
  float rg0[9], rg1[9], rg2[9], rg3[9], rg4[9];
#pragma unroll
  for (int k = 0; k < 9; ++k) { rg0[k]=0.f; rg1[k]=0.f; rg2[k]=0.f; rg3[k]=0.f; rg4[k]=0.f; }
  float a0=0.f, a1=0.f, a2=0.f, a3=0.f, a4=0.f;
  float lsum = 0.0f;

  float4 px4[3], py4[3];
  prefetch(0, px4, py4);               // plane step 0

#pragma unroll
  for (int ss = 0; ss <= NREAL; ++ss) {
    // prefetch plane ss+1 (consumed by S2 next superstep)
    float4 nx4[3], ny4[3];
    if (ss + 1 < NREAL) prefetch(ss + 1, nx4, ny4);

    // ---- S2 (plane ss): W-sums -> srow[ss&1]
    if (ss < NREAL && s2a) {
      float xv[12], yv[12];
#pragma unroll
      for (int k = 0; k < 3; ++k) {
        *(float4*)&xv[4 * k] = px4[k];
        *(float4*)&yv[4 * k] = py4[k];
      }
      float s0=0.f, s1=0.f, s2=0.f, s3=0.f, s4=0.f;
#pragma unroll
      for (int k = 0; k < 9; ++k) {
        s0 += xv[k]; s1 += yv[k];
        s2 = fmaf(xv[k], xv[k], s2);
        s3 = fmaf(yv[k], yv[k], s3);
        s4 = fmaf(xv[k], yv[k], s4);
      }
      float* wb = &srowF[ss & 1][(seg * 4) * 28 + r2];
      wb[0 * SR_FS] = s0; wb[1 * SR_FS] = s1; wb[2 * SR_FS] = s2;
      wb[3 * SR_FS] = s3; wb[4 * SR_FS] = s4;
#pragma unroll
      for (int t = 1; t < 4; ++t) {
        const float xn = xv[8 + t], xo = xv[t - 1];
        const float yn = yv[8 + t], yo = yv[t - 1];
        s0 += xn - xo;
        s1 += yn - yo;
        s2 += fmaf(xn, xn, -(xo * xo));
        s3 += fmaf(yn, yn, -(yo * yo));
        s4 += fmaf(xn, yn, -(xo * yo));
        float* wt = wb + t * 28;
        wt[0 * SR_FS] = s0; wt[1 * SR_FS] = s1; wt[2 * SR_FS] = s2;
        wt[3 * SR_FS] = s3; wt[4 * SR_FS] = s4;
      }
    }

    // ---- S3 (plane ss-1): H-sums srow[(ss-1)&1] -> scol[(ss-1)&1]
    if (ss >= 1 && s3a) {
      const float* rp = &srowF[(ss - 1) & 1][f3 * SR_FS + wl3 * 28];
      float rv[24];
#pragma unroll
      for (int t = 0; t < 6; ++t) *(float4*)&rv[4 * t] = *(const float4*)&rp[4 * t];
      float acc = rv[0];
#pragma unroll
      for (int t = 1; t < 9; ++t) acc += rv[t];
      float ov[16];
      ov[0] = acc;
#pragma unroll
      for (int o = 1; o < 16; ++o) { acc += rv[o + 8] - rv[o - 1]; ov[o] = acc; }
      float* cp = &scolF[(ss - 1) & 1][f3 * SC_FS + wl3 * 20];
#pragma unroll
      for (int t = 0; t < 4; ++t)
        *(float4*)&cp[4 * t] = make_float4(ov[4*t], ov[4*t+1], ov[4*t+2], ov[4*t+3]);
    }

    __syncthreads();   // single barrier per superstep (see hazard matrix above)

    // ---- S4 (plane ss-1): ring update + emit (all 256 threads)
    if (ss >= 1) {
      const int s  = ss - 1;
      const int sl = s % 9;
      const float* c = &scolF[s & 1][ow * 20 + oh];
      const float g0 = c[0*SC_FS], g1 = c[1*SC_FS], g2 = c[2*SC_FS],
                  g3 = c[3*SC_FS], g4 = c[4*SC_FS];
      a0 += g0 - rg0[sl]; rg0[sl] = g0;
      a1 += g1 - rg1[sl]; rg1[sl] = g1;
      a2 += g2 - rg2[sl]; rg2[sl] = g2;
      a3 += g3 - rg3[sl]; rg3[sl] = g3;
      a4 += g4 - rg4[sl]; rg4[sl] = g4;
      if (s >= 8) {
        const float cross = fmaf(-a0 * INV_WIN, a1, a4);
        const float iv = fmaxf(fmaf(-a0 * INV_WIN, a0, a2), EPSV);
        const float jv = fmaxf(fmaf(-a1 * INV_WIN, a1, a3), EPSV);
        lsum += (cross * cross) / (iv * jv);
      }
    }

    if (ss + 1 < NREAL) {
#pragma unroll
      for (int k = 0; k < 3; ++k) { px4[k] = nx4[k]; py4[k] = ny4[k]; }
    }
  }

  // ---- block reduction
#pragma unroll
  for (int off = 32; off > 0; off >>= 1) lsum += __shfl_down(lsum, off);
  if ((tid & 63) == 0) swsum[tid >> 6] = lsum;
  __syncthreads();
  if (tid == 0) bsum[nl] = swsum[0] + swsum[1] + swsum[2] + swsum[3];
}

__global__ __launch_bounds__(256)
void ncc_finalize(const float* __restrict__ bsum, float* __restrict__ out) {
  double s = 0.0;
  for (int i = threadIdx.x; i < NBLK; i += 256) s += (double)bsum[i];
#pragma unroll
  for (int off = 32; off > 0; off >>= 1) s += __shfl_down(s, off);
  __shared__ double sh[4];
  if ((threadIdx.x & 63) == 0) sh[threadIdx.x >> 6] = s;
  __syncthreads();
  if (threadIdx.x == 0)
    out[0] = (float)(-(sh[0] + sh[1] + sh[2] + sh[3]) / NTOT);
}

extern "C" void kernel_launch(void* const* d_in, const int* in_sizes, int n_in,
                              void* d_out, int out_size, void* d_ws, size_t ws_size,
                              hipStream_t stream) {
  const float* x = (const float*)d_in[0];
  const float* y = (const float*)d_in[1];
  float* bsum = (float*)d_ws;          // 3360 floats, fully rewritten every call
  float* out  = (float*)d_out;

  ncc_fused<<<dim3(NBLK), dim3(256), 0, stream>>>(x, y, bsum);
  ncc_finalize<<<1, dim3(256), 0, stream>>>(bsum, out);
}

// Round 2
// 280.928 us; speedup vs baseline: 1.5412x; 1.5412x over previous
//
#include <hip/hip_runtime.h>

namespace {

constexpr int BD = 2;
constexpr int DD = 160, HH = 192, WW = 224;
constexpr float INV_WIN = 1.0f / 729.0f;
constexpr float EPSV = 1e-5f;

constexpr int TH = 16, TW = 16;          // output tile (H x W)
constexpr int DC = 16;                   // output planes per d-chunk
constexpr int NREAL = DC + 8;            // 24 input plane steps (single-plane supersteps)
constexpr int NCH = DD / DC;             // 10
constexpr int GX = WW / TW;              // 14
constexpr int GY = HH / TH;              // 12
constexpr int GZ = BD * NCH;             // 20
constexpr int NBLK = GX * GY * GZ;       // 3360
constexpr int NXCD = 8;
constexpr int CPX = NBLK / NXCD;         // 420 (NBLK % 8 == 0 -> bijective swizzle)
constexpr double NTOT = (double)BD * DD * HH * WW;

// srow: [parity][field][w*28 + row], rows 0..23 (pad 28). Per-plane layout
// identical to the audited pair version (SR_FS=452: f-shift/4=113==1 mod 8;
// parity stride SR_PL=2280 is wave-uniform -> no bank effect).
// S2 b32 scatter 2/bank; S3 b128 reads uniform /quad.
constexpr int SR_FS = 452;
constexpr int SR_PL = 2280;
// scol: [parity][field][w*20 + oh]. SC_FS=324. S3 b128 writes uniform /quad;
// S4 b32 reads exactly 2/bank. Parity stride SC_PL=1620 wave-uniform.
constexpr int SC_FS = 324;
constexpr int SC_PL = 1620;

} // namespace

// Single-plane supersteps, ONE barrier per superstep:
//   iter ss: [prefetch(ss+1) | S2(ss)->srow[ss&1] | S3(ss-1): srow[(ss-1)&1]->scol[(ss-1)&1]]
//            barrier
//            [S4(ss-1): read scol[(ss-1)&1]]
// Hazard matrix (all separated by the single barrier C):
//   S2(ss) W srow[ss&1]      vs S3(ss-1) R srow[(ss-1)&1] : different parity, same epoch OK
//   S3(ss) R srow[ss&1]      vs S2(ss)   W                : C(ss) between
//   S2(ss+2) W srow[ss&1]    vs S3(ss)   R                : C(ss+1) between
//   S4(ss-1) R scol[(ss-1)&1] vs S3(ss-1) W               : C(ss) between
//   S3(ss) W scol[ss&1]      vs S4(ss-1) R (other parity) : same epoch OK
//   S3(ss+1) W scol[ss&1]    vs S4(ss-2) R scol[ss&1]     : C(ss) between
// LDS: 2*2280*4 + 2*1620*4 + 16 = 31216 B -> 5 blocks/CU.
// NOTE R1 post-mortem: __launch_bounds__(256,5) forced VGPRs 84->48 and the
// 45-float D-ring spilled to scratch (WRITE_SIZE 111->439 MB, 3x slower).
// Plain (256) compiles to ~84 VGPR -> 6 waves/SIMD possible; occupancy is
// then LDS-limited at 5 blocks/CU with ZERO spill. Do not re-add a min-waves
// hint here.
__global__ __launch_bounds__(256)
void ncc_fused(const float* __restrict__ x, const float* __restrict__ y,
               float* __restrict__ bsum) {
  const int tid = threadIdx.x;

  // XCD-chunked swizzle: consecutive hardware blocks round-robin XCDs; give
  // each XCD a contiguous chunk of the (x,y,z) space so W/H-halo re-reads of
  // neighbor tiles hit the same-XCD L2.
  const int lid = (int)blockIdx.x;
  const int nl  = (lid & (NXCD - 1)) * CPX + (lid >> 3);
  const int zb  = nl / (GX * GY);
  const int rem = nl - zb * (GX * GY);
  const int by  = rem / GX;
  const int bx  = rem - by * GX;

  const int w0 = bx * TW;
  const int h0 = by * TH;
  const int b  = zb / NCH;
  const int d0 = (zb - b * NCH) * DC;

  __shared__ __align__(16) float srowF[2][SR_PL];  // 18240 B
  __shared__ __align__(16) float scolF[2][SC_PL];  // 12960 B
  __shared__ float swsum[4];

  // ---- S2 roles: tids 0..95 = 24 rows x 4 col-segments, 12-wide register
  // window -> 4 sliding 9-tap W-sums x 5 fields (one plane per superstep).
  const bool s2a = tid < 96;
  const int r2  = tid >> 2;            // input row 0..23
  const int seg = tid & 3;
  const int gh  = h0 - 4 + r2;
  const int gw0 = w0 - 4 + seg * 4;    // 16B aligned
  const bool hok = (unsigned)gh < (unsigned)HH;
  const bool fastw = (gw0 >= 0) && (gw0 + 11 < WW);
  const unsigned plane = (unsigned)HH * WW;

  auto prefetch = [&](int s, float4* vx, float4* vy) {
    const int din = d0 - 4 + s;
    const float4 z = make_float4(0.f, 0.f, 0.f, 0.f);
    vx[0] = vx[1] = vx[2] = z;
    vy[0] = vy[1] = vy[2] = z;
    if (s2a && hok && (din >= 0) && (din < DD)) {
      const unsigned rb = ((unsigned)b * DD + (unsigned)din) * plane + (unsigned)gh * WW;
      if (fastw) {
        const float4* px = (const float4*)(x + rb + gw0);
        const float4* py = (const float4*)(y + rb + gw0);
        vx[0] = px[0]; vx[1] = px[1]; vx[2] = px[2];
        vy[0] = py[0]; vy[1] = py[1]; vy[2] = py[2];
      } else {
        float* fx = (float*)vx;
        float* fy = (float*)vy;
#pragma unroll
        for (int e = 0; e < 12; ++e) {
          const int gw = gw0 + e;
          if ((unsigned)gw < (unsigned)WW) {
            fx[e] = x[rb + gw];
            fy[e] = y[rb + gw];
          }
        }
      }
    }
  };

  // ---- S3 roles: tids 96..175 = 5 fields x 16 w (disjoint from S2 threads;
  // wave0: S2, wave1: half S2 + half S3, wave2: 3/4 S3, wave3: S4-only).
  const bool s3a = (tid >= 96) && (tid < 176);
  const int t3  = tid - 96;
  const int f3  = t3 >> 4;
  const int wl3 = t3 & 15;

  const int ow = tid & 15;
  const int oh = tid >> 4;

  // D-ring: 9 slots x 5 fields; slot indices static after full unroll.
  float rg0[9], rg1[9], rg2[9], rg3[9], rg4[9];
#pragma unroll
  for (int k = 0; k < 9; ++k) { rg0[k]=0.f; rg1[k]=0.f; rg2[k]=0.f; rg3[k]=0.f; rg4[k]=0.f; }
  float a0=0.f, a1=0.f, a2=0.f, a3=0.f, a4=0.f;
  float lsum = 0.0f;

  float4 px4[3], py4[3];
  prefetch(0, px4, py4);               // plane step 0

#pragma unroll
  for (int ss = 0; ss <= NREAL; ++ss) {
    // prefetch plane ss+1 (consumed by S2 next superstep)
    float4 nx4[3], ny4[3];
    if (ss + 1 < NREAL) prefetch(ss + 1, nx4, ny4);

    // ---- S2 (plane ss): W-sums -> srow[ss&1]
    if (ss < NREAL && s2a) {
      float xv[12], yv[12];
#pragma unroll
      for (int k = 0; k < 3; ++k) {
        *(float4*)&xv[4 * k] = px4[k];
        *(float4*)&yv[4 * k] = py4[k];
      }
      float s0=0.f, s1=0.f, s2=0.f, s3=0.f, s4=0.f;
#pragma unroll
      for (int k = 0; k < 9; ++k) {
        s0 += xv[k]; s1 += yv[k];
        s2 = fmaf(xv[k], xv[k], s2);
        s3 = fmaf(yv[k], yv[k], s3);
        s4 = fmaf(xv[k], yv[k], s4);
      }
      float* wb = &srowF[ss & 1][(seg * 4) * 28 + r2];
      wb[0 * SR_FS] = s0; wb[1 * SR_FS] = s1; wb[2 * SR_FS] = s2;
      wb[3 * SR_FS] = s3; wb[4 * SR_FS] = s4;
#pragma unroll
      for (int t = 1; t < 4; ++t) {
        const float xn = xv[8 + t], xo = xv[t - 1];
        const float yn = yv[8 + t], yo = yv[t - 1];
        s0 += xn - xo;
        s1 += yn - yo;
        s2 += fmaf(xn, xn, -(xo * xo));
        s3 += fmaf(yn, yn, -(yo * yo));
        s4 += fmaf(xn, yn, -(xo * yo));
        float* wt = wb + t * 28;
        wt[0 * SR_FS] = s0; wt[1 * SR_FS] = s1; wt[2 * SR_FS] = s2;
        wt[3 * SR_FS] = s3; wt[4 * SR_FS] = s4;
      }
    }

    // ---- S3 (plane ss-1): H-sums srow[(ss-1)&1] -> scol[(ss-1)&1]
    if (ss >= 1 && s3a) {
      const float* rp = &srowF[(ss - 1) & 1][f3 * SR_FS + wl3 * 28];
      float rv[24];
#pragma unroll
      for (int t = 0; t < 6; ++t) *(float4*)&rv[4 * t] = *(const float4*)&rp[4 * t];
      float acc = rv[0];
#pragma unroll
      for (int t = 1; t < 9; ++t) acc += rv[t];
      float ov[16];
      ov[0] = acc;
#pragma unroll
      for (int o = 1; o < 16; ++o) { acc += rv[o + 8] - rv[o - 1]; ov[o] = acc; }
      float* cp = &scolF[(ss - 1) & 1][f3 * SC_FS + wl3 * 20];
#pragma unroll
      for (int t = 0; t < 4; ++t)
        *(float4*)&cp[4 * t] = make_float4(ov[4*t], ov[4*t+1], ov[4*t+2], ov[4*t+3]);
    }

    __syncthreads();   // single barrier per superstep (see hazard matrix above)

    // ---- S4 (plane ss-1): ring update + emit (all 256 threads)
    if (ss >= 1) {
      const int s  = ss - 1;
      const int sl = s % 9;
      const float* c = &scolF[s & 1][ow * 20 + oh];
      const float g0 = c[0*SC_FS], g1 = c[1*SC_FS], g2 = c[2*SC_FS],
                  g3 = c[3*SC_FS], g4 = c[4*SC_FS];
      a0 += g0 - rg0[sl]; rg0[sl] = g0;
      a1 += g1 - rg1[sl]; rg1[sl] = g1;
      a2 += g2 - rg2[sl]; rg2[sl] = g2;
      a3 += g3 - rg3[sl]; rg3[sl] = g3;
      a4 += g4 - rg4[sl]; rg4[sl] = g4;
      if (s >= 8) {
        const float cross = fmaf(-a0 * INV_WIN, a1, a4);
        const float iv = fmaxf(fmaf(-a0 * INV_WIN, a0, a2), EPSV);
        const float jv = fmaxf(fmaf(-a1 * INV_WIN, a1, a3), EPSV);
        lsum += (cross * cross) / (iv * jv);
      }
    }

    if (ss + 1 < NREAL) {
#pragma unroll
      for (int k = 0; k < 3; ++k) { px4[k] = nx4[k]; py4[k] = ny4[k]; }
    }
  }

  // ---- block reduction
#pragma unroll
  for (int off = 32; off > 0; off >>= 1) lsum += __shfl_down(lsum, off);
  if ((tid & 63) == 0) swsum[tid >> 6] = lsum;
  __syncthreads();
  if (tid == 0) bsum[nl] = swsum[0] + swsum[1] + swsum[2] + swsum[3];
}

__global__ __launch_bounds__(256)
void ncc_finalize(const float* __restrict__ bsum, float* __restrict__ out) {
  double s = 0.0;
  for (int i = threadIdx.x; i < NBLK; i += 256) s += (double)bsum[i];
#pragma unroll
  for (int off = 32; off > 0; off >>= 1) s += __shfl_down(s, off);
  __shared__ double sh[4];
  if ((threadIdx.x & 63) == 0) sh[threadIdx.x >> 6] = s;
  __syncthreads();
  if (threadIdx.x == 0)
    out[0] = (float)(-(sh[0] + sh[1] + sh[2] + sh[3]) / NTOT);
}

extern "C" void kernel_launch(void* const* d_in, const int* in_sizes, int n_in,
                              void* d_out, int out_size, void* d_ws, size_t ws_size,
                              hipStream_t stream) {
  const float* x = (const float*)d_in[0];
  const float* y = (const float*)d_in[1];
  float* bsum = (float*)d_ws;          // 3360 floats, fully rewritten every call
  float* out  = (float*)d_out;

  ncc_fused<<<dim3(NBLK), dim3(256), 0, stream>>>(x, y, bsum);
  ncc_finalize<<<1, dim3(256), 0, stream>>>(bsum, out);
}

// Round 3
// 214.226 us; speedup vs baseline: 2.0211x; 1.3114x over previous
//
#include <hip/hip_runtime.h>

namespace {

constexpr int BD = 2;
constexpr int DD = 160, HH = 192, WW = 224;
constexpr float INV_WIN = 1.0f / 729.0f;
constexpr float EPSV = 1e-5f;

constexpr int TH = 16, TW = 16;          // output tile (H x W)
constexpr int DC = 80;                   // output planes per d-chunk (was 16): halo 88/80=1.1x
constexpr int NREAL = DC + 8;            // 88 input plane steps = 44 pairs
constexpr int NPAIR = NREAL / 2;         // 44; superstep loop runs 45 = 5*9 (ring-aligned)
constexpr int NCH = DD / DC;             // 2
constexpr int GX = WW / TW;              // 14
constexpr int GY = HH / TH;              // 12
constexpr int GZ = BD * NCH;             // 4
constexpr int NBLK = GX * GY * GZ;       // 672  (<= 256 CU x 3 resident: whole grid co-resident)
constexpr int NXCD = 8;
constexpr int CPX = NBLK / NXCD;         // 84 (672 % 8 == 0 -> bijective swizzle)
constexpr double NTOT = (double)BD * DD * HH * WW;

// srow: [buf][plane][field][w*28 + row], rows 0..23 contiguous (pad 28).
// SR_FS=452 (f-shift /4=113==1 mod 8), SR_PL=2280 (==8 mod 32). Audited:
// S2 b32 scatter 2/bank; S3 b128 reads uniform /quad (incl. straddle waves).
constexpr int SR_FS = 452;
constexpr int SR_PL = 2280;
// scol: [plane][field][w*20 + o]. SC_FS=324, SC_PL=1620. S3 b128 writes
// uniform /quad; S4 b32 reads exactly 2/bank.
constexpr int SC_FS = 324;
constexpr int SC_PL = 1620;

} // namespace

// R0 pair-superstep structure (two barriers, 192-thread S2 / 160-thread S3,
// register D-ring) — measured best (115us fused). R2 lesson: single-plane
// supersteps halve per-epoch ILP and regress 1.65x; do NOT shrink epochs.
// R1 lesson: no min-waves launch_bounds hint (forces ring spill, 3x).
// New here vs R0: (a) XCD-chunked block swizzle (R2-proven: FETCH 348->78 MB),
// (b) DC=80 halo amortization (work/plane x0.69), (c) outer x5 rolled /
// inner x9 unrolled loop — 9 pair-supersteps = one full %9 ring period, so
// ring slot indices stay COMPILE-TIME (dynamic index => scratch spill).
__global__ __launch_bounds__(256)
void ncc_fused(const float* __restrict__ x, const float* __restrict__ y,
               float* __restrict__ bsum) {
  const int tid = threadIdx.x;

  // XCD-chunked swizzle: consecutive hardware blocks round-robin XCDs; give
  // each XCD a contiguous chunk of (x,y,z) so halo re-reads hit same-XCD L2.
  const int lid = (int)blockIdx.x;
  const int nl  = (lid & (NXCD - 1)) * CPX + (lid >> 3);
  const int zb  = nl / (GX * GY);
  const int rem = nl - zb * (GX * GY);
  const int by  = rem / GX;
  const int bx  = rem - by * GX;

  const int w0 = bx * TW;
  const int h0 = by * TH;
  const int b  = zb / NCH;
  const int d0 = (zb - b * NCH) * DC;

  __shared__ __align__(16) float srowF[2][2 * SR_PL];  // 36480 B (pair dbuf)
  __shared__ __align__(16) float scolF[2 * SC_PL];     // 12960 B
  __shared__ float swsum[4];

  // ---- S2 roles: tids 0..191 = 2 planes x 24 rows x 4 col-segments,
  // 12-wide register window -> 4 sliding 9-tap W-sums x 5 fields.
  const bool s2a = tid < 192;
  const int p2  = tid / 96;
  const int t96 = tid - 96 * p2;
  const int r2  = t96 >> 2;            // input row 0..23
  const int seg = tid & 3;
  const int gh  = h0 - 4 + r2;
  const int gw0 = w0 - 4 + seg * 4;    // 16B aligned
  const bool hok = (unsigned)gh < (unsigned)HH;
  const bool fastw = (gw0 >= 0) && (gw0 + 11 < WW);
  const unsigned plane = (unsigned)HH * WW;

  auto prefetch = [&](int s, float4* vx, float4* vy) {
    const int din = d0 - 4 + s;
    const float4 z = make_float4(0.f, 0.f, 0.f, 0.f);
    vx[0] = vx[1] = vx[2] = z;
    vy[0] = vy[1] = vy[2] = z;
    if (s2a && hok && (s < NREAL) && (din >= 0) && (din < DD)) {
      const unsigned rb = ((unsigned)b * DD + (unsigned)din) * plane + (unsigned)gh * WW;
      if (fastw) {
        const float4* px = (const float4*)(x + rb + gw0);
        const float4* py = (const float4*)(y + rb + gw0);
        vx[0] = px[0]; vx[1] = px[1]; vx[2] = px[2];
        vy[0] = py[0]; vy[1] = py[1]; vy[2] = py[2];
      } else {
        float* fx = (float*)vx;
        float* fy = (float*)vy;
#pragma unroll
        for (int e = 0; e < 12; ++e) {
          const int gw = gw0 + e;
          if ((unsigned)gw < (unsigned)WW) {
            fx[e] = x[rb + gw];
            fy[e] = y[rb + gw];
          }
        }
      }
    }
  };

  // ---- S3 roles: tids 96..255 = 2 planes x 5 fields x 16 w (wave balance:
  // wave0 S2-only, wave3 S3-only, waves1-2 mixed).
  const int t3  = tid - 96;
  const int p3  = t3 / 80;
  const int r3  = t3 - 80 * p3;
  const int f3  = r3 >> 4;
  const int wl3 = r3 & 15;

  const int ow = tid & 15;
  const int oh = tid >> 4;

  // D-ring: 9 slots x 5 fields; slot indices static (inner loop unrolled x9
  // = exactly one ring period: (18*it + k) % 9 == k % 9).
  float rg0[9], rg1[9], rg2[9], rg3[9], rg4[9];
#pragma unroll
  for (int k = 0; k < 9; ++k) { rg0[k]=0.f; rg1[k]=0.f; rg2[k]=0.f; rg3[k]=0.f; rg4[k]=0.f; }
  float a0=0.f, a1=0.f, a2=0.f, a3=0.f, a4=0.f;
  float lsum = 0.0f;

  float4 px4[3], py4[3];
  prefetch(p2, px4, py4);               // pair 0

  // Pipelined supersteps: S2 stages pair ss; S3/S4 consume pair ss-1.
  // 45 total iterations = 5 outer x 9 inner.
#pragma unroll 1
  for (int it = 0; it < (NPAIR + 1) / 9; ++it) {
#pragma unroll
    for (int u = 0; u < 9; ++u) {
      const int ss = 9 * it + u;

      // prefetch pair ss+1 (consumed by S2 next superstep)
      float4 nx4[3], ny4[3];
      if (ss + 1 < NPAIR) prefetch(2 * (ss + 1) + p2, nx4, ny4);

      // ---- S2 (pair ss): W-sums -> srow[ss&1]. Independent of S3 below.
      if (ss < NPAIR && s2a) {
        float xv[12], yv[12];
#pragma unroll
        for (int k = 0; k < 3; ++k) {
          *(float4*)&xv[4 * k] = px4[k];
          *(float4*)&yv[4 * k] = py4[k];
        }
        float s0=0.f, s1=0.f, s2=0.f, s3=0.f, s4=0.f;
#pragma unroll
        for (int k = 0; k < 9; ++k) {
          s0 += xv[k]; s1 += yv[k];
          s2 = fmaf(xv[k], xv[k], s2);
          s3 = fmaf(yv[k], yv[k], s3);
          s4 = fmaf(xv[k], yv[k], s4);
        }
        float* wb = &srowF[ss & 1][p2 * SR_PL + (seg * 4) * 28 + r2];
        wb[0 * SR_FS] = s0; wb[1 * SR_FS] = s1; wb[2 * SR_FS] = s2;
        wb[3 * SR_FS] = s3; wb[4 * SR_FS] = s4;
#pragma unroll
        for (int t = 1; t < 4; ++t) {
          const float xn = xv[8 + t], xo = xv[t - 1];
          const float yn = yv[8 + t], yo = yv[t - 1];
          s0 += xn - xo;
          s1 += yn - yo;
          s2 += fmaf(xn, xn, -(xo * xo));
          s3 += fmaf(yn, yn, -(yo * yo));
          s4 += fmaf(xn, yn, -(xo * yo));
          float* wt = wb + t * 28;
          wt[0 * SR_FS] = s0; wt[1 * SR_FS] = s1; wt[2 * SR_FS] = s2;
          wt[3 * SR_FS] = s3; wt[4 * SR_FS] = s4;
        }
      }

      // ---- S3 (pair ss-1): H-sums from srow[(ss-1)&1] -> scol.
      // No barrier needed vs S2: different srow buffer (written last
      // superstep, separated by barrier E(ss-1)).
      if (ss >= 1 && tid >= 96) {
        const float* rp = &srowF[(ss - 1) & 1][p3 * SR_PL + f3 * SR_FS + wl3 * 28];
        float rv[24];
#pragma unroll
        for (int t = 0; t < 6; ++t) *(float4*)&rv[4 * t] = *(const float4*)&rp[4 * t];
        float acc = rv[0];
#pragma unroll
        for (int t = 1; t < 9; ++t) acc += rv[t];
        float ov[16];
        ov[0] = acc;
#pragma unroll
        for (int o = 1; o < 16; ++o) { acc += rv[o + 8] - rv[o - 1]; ov[o] = acc; }
        float* cp = &scolF[p3 * SC_PL + f3 * SC_FS + wl3 * 20];
#pragma unroll
        for (int t = 0; t < 4; ++t)
          *(float4*)&cp[4 * t] = make_float4(ov[4*t], ov[4*t+1], ov[4*t+2], ov[4*t+3]);
      }
      __syncthreads();   // C: scol visible (also orders S2 writes vs next S3)

      // ---- S4 (pair ss-1): ring update + emit (all 256 threads)
      if (ss >= 1) {
        // ring slots: sA = 2*(ss-1) = 18*it + 2u - 2  ->  slA = (2u+7)%9
        const int sA  = 2 * (ss - 1);
        const int sB  = sA + 1;
        const int slA = (2 * u + 7) % 9;   // compile-time (u unrolled)
        const int slB = (2 * u + 8) % 9;
        const float* cA = &scolF[ow * 20 + oh];
        const float* cB = cA + SC_PL;
        const float gA0 = cA[0*SC_FS], gA1 = cA[1*SC_FS], gA2 = cA[2*SC_FS],
                    gA3 = cA[3*SC_FS], gA4 = cA[4*SC_FS];
        const float gB0 = cB[0*SC_FS], gB1 = cB[1*SC_FS], gB2 = cB[2*SC_FS],
                    gB3 = cB[3*SC_FS], gB4 = cB[4*SC_FS];

        a0 += gA0 - rg0[slA]; rg0[slA] = gA0;
        a1 += gA1 - rg1[slA]; rg1[slA] = gA1;
        a2 += gA2 - rg2[slA]; rg2[slA] = gA2;
        a3 += gA3 - rg3[slA]; rg3[slA] = gA3;
        a4 += gA4 - rg4[slA]; rg4[slA] = gA4;
        if (sA >= 8) {
          const float cross = fmaf(-a0 * INV_WIN, a1, a4);
          const float iv = fmaxf(fmaf(-a0 * INV_WIN, a0, a2), EPSV);
          const float jv = fmaxf(fmaf(-a1 * INV_WIN, a1, a3), EPSV);
          lsum += (cross * cross) / (iv * jv);
        }
        a0 += gB0 - rg0[slB]; rg0[slB] = gB0;
        a1 += gB1 - rg1[slB]; rg1[slB] = gB1;
        a2 += gB2 - rg2[slB]; rg2[slB] = gB2;
        a3 += gB3 - rg3[slB]; rg3[slB] = gB3;
        a4 += gB4 - rg4[slB]; rg4[slB] = gB4;
        if (sB >= 8) {
          const float cross = fmaf(-a0 * INV_WIN, a1, a4);
          const float iv = fmaxf(fmaf(-a0 * INV_WIN, a0, a2), EPSV);
          const float jv = fmaxf(fmaf(-a1 * INV_WIN, a1, a3), EPSV);
          lsum += (cross * cross) / (iv * jv);
        }
      }
      __syncthreads();   // E: S4 scol-reads done before S3(ss+1) overwrites;
                         //    S2(ss) srow writes visible to S3(ss+1).
      if (ss + 1 < NPAIR) {
#pragma unroll
        for (int k = 0; k < 3; ++k) { px4[k] = nx4[k]; py4[k] = ny4[k]; }
      }
    }
  }

  // ---- block reduction
#pragma unroll
  for (int off = 32; off > 0; off >>= 1) lsum += __shfl_down(lsum, off);
  if ((tid & 63) == 0) swsum[tid >> 6] = lsum;
  __syncthreads();
  if (tid == 0) bsum[nl] = swsum[0] + swsum[1] + swsum[2] + swsum[3];
}

__global__ __launch_bounds__(256)
void ncc_finalize(const float* __restrict__ bsum, float* __restrict__ out) {
  double s = 0.0;
  for (int i = threadIdx.x; i < NBLK; i += 256) s += (double)bsum[i];
#pragma unroll
  for (int off = 32; off > 0; off >>= 1) s += __shfl_down(s, off);
  __shared__ double sh[4];
  if ((threadIdx.x & 63) == 0) sh[threadIdx.x >> 6] = s;
  __syncthreads();
  if (threadIdx.x == 0)
    out[0] = (float)(-(sh[0] + sh[1] + sh[2] + sh[3]) / NTOT);
}

extern "C" void kernel_launch(void* const* d_in, const int* in_sizes, int n_in,
                              void* d_out, int out_size, void* d_ws, size_t ws_size,
                              hipStream_t stream) {
  const float* x = (const float*)d_in[0];
  const float* y = (const float*)d_in[1];
  float* bsum = (float*)d_ws;          // 672 floats, fully rewritten every call
  float* out  = (float*)d_out;

  ncc_fused<<<dim3(NBLK), dim3(256), 0, stream>>>(x, y, bsum);
  ncc_finalize<<<1, dim3(256), 0, stream>>>(bsum, out);
}